// Round 7
// baseline (276.264 us; speedup 1.0000x reference)
//
#include <hip/hip_runtime.h>

#define B_TOTAL 524288
#define TILE_B 128
#define NBLK (B_TOTAL / TILE_B)   // 4096
#define NTHR 512

// MSE weights after VAR_IDX mapping: ch0:0.15 ch1:0.15 ch2:0.5 ch3:0.1 ch4:0.1
// step_w = [0.48, 0.24, 0.16, 0.12]
// One thread per (b,s): b=tid>>2, s=tid&3. prev = pred[s-1] from LDS (s>0) or
// inseq[b,7,:] (s==0). Staging via global_load_lds width=16, LDS dest linear,
// XOR swizzle applied to the GLOBAL source index (involution).
// Single kernel: per-block partials (agent-scope stores) + device-scope ticket;
// last block to finish reduces and writes the scalar (round-4-validated pattern).

__device__ __forceinline__ void gload_lds16(const void* g, void* l) {
    __builtin_amdgcn_global_load_lds(
        (const __attribute__((address_space(1))) void*)g,
        (__attribute__((address_space(3))) void*)l, 16, 0, 0);
}

__global__ __launch_bounds__(NTHR) void loss_fused(
    const float* __restrict__ pred,    // (B,4,16)
    const float* __restrict__ target,  // (B,4,16)
    const float* __restrict__ inseq,   // (B,8,16)
    const float* __restrict__ scale,   // (16)
    const float* __restrict__ mean,    // (16)
    float* __restrict__ partials,      // (10, NBLK)
    int* __restrict__ counter,         // zeroed by memset node each launch
    float* __restrict__ out)
{
    // sp: pred ch0-11, 1536 float4 = 24KB; st: target ch0-7, 1024 float4 = 16KB
    // Total exactly 40KB -> 4 blocks/CU. Reduction scratch + tot + flag alias st.
    __shared__ float4 sp[TILE_B * 12];
    __shared__ float4 st[TILE_B * 8];
    float* sf = reinterpret_cast<float*>(st);
    // sf[0..79]  = red[wave][slot]; sf[80..95] = tot[10] (last block); ((int*)sf)[96] = amLast

    const int tid = threadIdx.x;
    const size_t tile0 = (size_t)blockIdx.x * TILE_B;

    const float4* prg = reinterpret_cast<const float4*>(pred) + tile0 * 16;
    const float4* tgg = reinterpret_cast<const float4*>(target) + tile0 * 16;

    // ---- async stage pred ch0-11: LDS slot j <- global element swz(j) ----
#pragma unroll
    for (int it = 0; it < 3; ++it) {
        int j = it * NTHR + tid;
        int i = j ^ ((j >> 3) & 7);
        int r = i / 3, k = i - r * 3;
        gload_lds16(prg + r * 4 + k, sp + j);
    }
    // ---- async stage target ch0-7 ----
#pragma unroll
    for (int it = 0; it < 2; ++it) {
        int j = it * NTHR + tid;
        int i = j ^ ((j >> 3) & 7);
        gload_lds16(tgg + ((i >> 1) << 2) + (i & 1), st + j);
    }

    const int b = tid >> 2;
    const int s = tid & 3;

    // prev channels needed: 0,2,5,7,8,9,11
    float pv0 = 0.f, pv2 = 0.f, pv5 = 0.f, pv7 = 0.f, pv8 = 0.f, pv9 = 0.f, pv11 = 0.f;
    if (s == 0) {
        const float4* iq = reinterpret_cast<const float4*>(inseq + (tile0 + (size_t)b) * 128 + 112);
        float4 q0 = iq[0], q1 = iq[1], q2 = iq[2];
        pv0 = q0.x; pv2 = q0.z; pv5 = q1.y; pv7 = q1.w;
        pv8 = q2.x; pv9 = q2.y; pv11 = q2.w;
    }

    const float sc0 = scale[0], sc2 = scale[2], sc3 = scale[3], sc4 = scale[4];
    const float sc5 = scale[5], sc7 = scale[7], sc8 = scale[8], sc9 = scale[9], sc11 = scale[11];
    const float mn3 = mean[3], mn4 = mean[4];
    const float sw = (s == 0) ? 0.48f : (s == 1) ? 0.24f : (s == 2) ? 0.16f : 0.12f;

    __syncthreads();   // drains vmcnt (incl. global_load_lds) then barrier

    auto ldp = [&](int row, int w) -> float4 {
        int i = row * 3 + w;
        return sp[i ^ ((i >> 3) & 7)];
    };
    auto ldt = [&](int row, int h) -> float4 {
        int i = row * 2 + h;
        return st[i ^ ((i >> 3) & 7)];
    };

    const int row = b * 4 + s;
    if (s != 0) {
        float4 q0 = ldp(row - 1, 0), q1 = ldp(row - 1, 1), q2 = ldp(row - 1, 2);
        pv0 = q0.x; pv2 = q0.z; pv5 = q1.y; pv7 = q1.w;
        pv8 = q2.x; pv9 = q2.y; pv11 = q2.w;
    }

    float4 p0 = ldp(row, 0), p1 = ldp(row, 1), p2 = ldp(row, 2);
    float4 t0 = ldt(row, 0), t1 = ldt(row, 1);

    // ---- MSE ch0-4, step-weighted ----
    float d0 = p0.x - t0.x, d1 = p0.y - t0.y, d2 = p0.z - t0.z;
    float d3 = p0.w - t0.w, d4 = p1.x - t1.x;
    float acc_mse = sw * (0.15f * d0 * d0 + 0.15f * d1 * d1 + 0.5f * d2 * d2 +
                          0.1f * d3 * d3 + 0.1f * d4 * d4);

    // ---- heat balance (per-step sums; s fixed per thread) ----
    float air = p0.w * sc3 + mn3;
    float water = p1.x * sc4 + mn4;
    float hdf = air - water;
    float hn = hdf * hdf;
    float hd = air * air;

    // ---- frost (ch2) / pressure (ch0): mean cancels in pd-pv ----
    float fr = fmaxf((pv2 - p0.z) * sc2, 0.f);
    float pg = fmaxf((pv0 - p0.x) * sc0, 0.f) * 0.5f;
    float rest = fr * fr + pg * pg;
    // ---- temp penalty ch 5,7,8,9,11 ----
    float t5 = fmaxf(fabsf(p1.y - pv5) * sc5 - 5.f, 0.f);
    float t7 = fmaxf(fabsf(p1.w - pv7) * sc7 - 5.f, 0.f);
    float t8 = fmaxf(fabsf(p2.x - pv8) * sc8 - 5.f, 0.f);
    float t9 = fmaxf(fabsf(p2.y - pv9) * sc9 - 5.f, 0.f);
    float t11 = fmaxf(fabsf(p2.w - pv11) * sc11 - 5.f, 0.f);
    rest += 0.1f * (t5 * t5 + t7 * t7 + t8 * t8 + t9 * t9 + t11 * t11);
    float acc_rest = sw * rest;

    __syncthreads();   // st reads done; safe to reuse as scratch

    // ---- in-block reductions ----
    const int lane = tid & 63;
    const int wave = tid >> 6;
#pragma unroll
    for (int off = 1; off < 64; off <<= 1) {
        acc_mse  += __shfl_xor(acc_mse, off, 64);
        acc_rest += __shfl_xor(acc_rest, off, 64);
    }
#pragma unroll
    for (int off = 4; off < 64; off <<= 1) {
        hn += __shfl_xor(hn, off, 64);
        hd += __shfl_xor(hd, off, 64);
    }
    if (lane == 0) { sf[wave * 10 + 0] = acc_mse; sf[wave * 10 + 1] = acc_rest; }
    if (lane < 4)  { sf[wave * 10 + 2 + lane] = hn; sf[wave * 10 + 6 + lane] = hd; }
    __syncthreads();

    if (tid < 10) {
        float v = 0.f;
#pragma unroll
        for (int w = 0; w < 8; ++w) v += sf[w * 10 + tid];
        __hip_atomic_store(&partials[tid * NBLK + blockIdx.x], v,
                           __ATOMIC_RELAXED, __HIP_MEMORY_SCOPE_AGENT);
        __threadfence();
    }
    __syncthreads();   // waits vmcnt(0): partials stores complete before ticket

    // ---- ticket: last block to finish reduces everything ----
    if (tid == 0) {
        int ticket = atomicAdd(counter, 1);   // device scope
        ((int*)sf)[96] = (ticket == NBLK - 1);
    }
    __syncthreads();
    if (!((int*)sf)[96]) return;

    __threadfence();
    float* tot = sf + 80;
    // wave w handles channels w and w+8 (<10): 64 coalesced agent loads per lane
    for (int c = wave; c < 10; c += 8) {
        float v = 0.f;
#pragma unroll 8
        for (int i = 0; i < NBLK / 64; ++i)
            v += __hip_atomic_load(&partials[(size_t)c * NBLK + i * 64 + lane],
                                   __ATOMIC_RELAXED, __HIP_MEMORY_SCOPE_AGENT);
#pragma unroll
        for (int off = 32; off; off >>= 1) v += __shfl_down(v, off, 64);
        if (lane == 0) tot[c] = v;
    }
    __syncthreads();

    if (tid == 0) {
        const float stepw[4] = {0.48f, 0.24f, 0.16f, 0.12f};
        const float invB = 1.0f / (float)B_TOTAL;
        float mse = tot[0] * invB;
        float phys = tot[1] * invB;
#pragma unroll
        for (int q = 0; q < 4; ++q) {
            float num = tot[2 + q] * invB;
            float den = tot[6 + q] * invB + 1e-6f;
            phys += stepw[q] * (num / den);
        }
        out[0] = mse + 0.1f * phys;
    }
}

extern "C" void kernel_launch(void* const* d_in, const int* in_sizes, int n_in,
                              void* d_out, int out_size, void* d_ws, size_t ws_size,
                              hipStream_t stream) {
    const float* pred   = (const float*)d_in[0];
    const float* target = (const float*)d_in[1];
    const float* inseq  = (const float*)d_in[2];
    const float* scale  = (const float*)d_in[3];
    const float* mean   = (const float*)d_in[4];
    float* out = (float*)d_out;
    float* partials = (float*)d_ws;                          // 10*NBLK floats = 160 KB
    int* counter = (int*)((char*)d_ws + 10 * NBLK * sizeof(float));

    hipMemsetAsync(counter, 0, sizeof(int), stream);         // graph-capturable memset node
    loss_fused<<<NBLK, NTHR, 0, stream>>>(pred, target, inseq, scale, mean,
                                          partials, counter, out);
}

// Round 8
// 61.632 us; speedup vs baseline: 4.4825x; 4.4825x over previous
//
#include <hip/hip_runtime.h>

#define B_TOTAL 524288
#define TILE_B 128
#define NBLK (B_TOTAL / TILE_B)   // 4096
#define NTHR 512

// MSE weights after VAR_IDX mapping: ch0:0.15 ch1:0.15 ch2:0.5 ch3:0.1 ch4:0.1
// step_w = [0.48, 0.24, 0.16, 0.12]
// One thread per (b,s): b=tid>>2, s=tid&3. prev = pred[s-1] from LDS (s>0) or
// inseq[b,7,:] (s==0, gathered via intra-group shuffles).
// Staging via global_load_lds width=16, LDS dest linear, XOR swizzle applied to
// the GLOBAL source index (involution). Two-kernel structure: fused variants
// (r4, r7) both collapsed codegen (VGPR clamp 32/20) — do not re-fuse.

__device__ __forceinline__ void gload_lds16(const void* g, void* l) {
    __builtin_amdgcn_global_load_lds(
        (const __attribute__((address_space(1))) void*)g,
        (__attribute__((address_space(3))) void*)l, 16, 0, 0);
}

__global__ __launch_bounds__(NTHR) void loss_partial(
    const float* __restrict__ pred,    // (B,4,16)
    const float* __restrict__ target,  // (B,4,16)
    const float* __restrict__ inseq,   // (B,8,16)
    const float* __restrict__ scale,   // (16)
    const float* __restrict__ mean,    // (16)
    float* __restrict__ partials)      // (10, NBLK) SoA
{
    // sp: pred ch0-11, 1536 float4 = 24KB; st: target ch0-7, 1024 float4 = 16KB
    // Total exactly 40KB -> 4 blocks/CU. Reduction scratch aliases st.
    __shared__ float4 sp[TILE_B * 12];
    __shared__ float4 st[TILE_B * 8];

    const int tid = threadIdx.x;
    const size_t tile0 = (size_t)blockIdx.x * TILE_B;

    const float4* prg = reinterpret_cast<const float4*>(pred) + tile0 * 16;
    const float4* tgg = reinterpret_cast<const float4*>(target) + tile0 * 16;

    // ---- async stage pred ch0-11: LDS slot j <- global element swz(j) ----
#pragma unroll
    for (int it = 0; it < 3; ++it) {
        int j = it * NTHR + tid;
        int i = j ^ ((j >> 3) & 7);
        int r = i / 3, k = i - r * 3;
        gload_lds16(prg + r * 4 + k, sp + j);
    }
    // ---- async stage target ch0-7 ----
#pragma unroll
    for (int it = 0; it < 2; ++it) {
        int j = it * NTHR + tid;
        int i = j ^ ((j >> 3) & 7);
        gload_lds16(tgg + ((i >> 1) << 2) + (i & 1), st + j);
    }

    const int b = tid >> 2;
    const int s = tid & 3;

    // ---- inseq[b,7,0:12]: lanes s=0,1,2 each load one float4 of the row ----
    // all three land in the SAME 64B line -> 1 instr, 16 lines/wave
    float4 q = make_float4(0.f, 0.f, 0.f, 0.f);
    if (s < 3) {
        const float4* iq = reinterpret_cast<const float4*>(inseq + (tile0 + (size_t)b) * 128 + 112);
        q = iq[s];
    }
    // gather to the s==0 thread of each 4-lane group
    const int lane = tid & 63;
    const int src1 = (lane & ~3) | 1;
    const int src2 = (lane & ~3) | 2;
    float a5  = __shfl(q.y, src1, 64);
    float a7  = __shfl(q.w, src1, 64);
    float a8  = __shfl(q.x, src2, 64);
    float a9  = __shfl(q.y, src2, 64);
    float a11 = __shfl(q.w, src2, 64);

    // prev channels needed: 0,2,5,7,8,9,11
    float pv0 = 0.f, pv2 = 0.f, pv5 = 0.f, pv7 = 0.f, pv8 = 0.f, pv9 = 0.f, pv11 = 0.f;
    if (s == 0) {
        pv0 = q.x; pv2 = q.z; pv5 = a5; pv7 = a7;
        pv8 = a8; pv9 = a9; pv11 = a11;
    }

    const float sc0 = scale[0], sc2 = scale[2], sc3 = scale[3], sc4 = scale[4];
    const float sc5 = scale[5], sc7 = scale[7], sc8 = scale[8], sc9 = scale[9], sc11 = scale[11];
    const float mn3 = mean[3], mn4 = mean[4];
    const float sw = (s == 0) ? 0.48f : (s == 1) ? 0.24f : (s == 2) ? 0.16f : 0.12f;

    __syncthreads();   // drains vmcnt (incl. global_load_lds DMA) then barrier

    auto ldp = [&](int row, int w) -> float4 {
        int i = row * 3 + w;
        return sp[i ^ ((i >> 3) & 7)];
    };
    auto ldt = [&](int row, int h) -> float4 {
        int i = row * 2 + h;
        return st[i ^ ((i >> 3) & 7)];
    };

    const int row = b * 4 + s;
    if (s != 0) {
        float4 q0 = ldp(row - 1, 0), q1 = ldp(row - 1, 1), q2 = ldp(row - 1, 2);
        pv0 = q0.x; pv2 = q0.z; pv5 = q1.y; pv7 = q1.w;
        pv8 = q2.x; pv9 = q2.y; pv11 = q2.w;
    }

    float4 p0 = ldp(row, 0), p1 = ldp(row, 1), p2 = ldp(row, 2);
    float4 t0 = ldt(row, 0), t1 = ldt(row, 1);

    // ---- MSE ch0-4, step-weighted ----
    float d0 = p0.x - t0.x, d1 = p0.y - t0.y, d2 = p0.z - t0.z;
    float d3 = p0.w - t0.w, d4 = p1.x - t1.x;
    float acc_mse = sw * (0.15f * d0 * d0 + 0.15f * d1 * d1 + 0.5f * d2 * d2 +
                          0.1f * d3 * d3 + 0.1f * d4 * d4);

    // ---- heat balance (per-step sums; s fixed per thread) ----
    float air = p0.w * sc3 + mn3;
    float water = p1.x * sc4 + mn4;
    float hdf = air - water;
    float hn = hdf * hdf;
    float hd = air * air;

    // ---- frost (ch2) / pressure (ch0): mean cancels in pd-pv ----
    float fr = fmaxf((pv2 - p0.z) * sc2, 0.f);
    float pg = fmaxf((pv0 - p0.x) * sc0, 0.f) * 0.5f;
    float rest = fr * fr + pg * pg;
    // ---- temp penalty ch 5,7,8,9,11 ----
    float t5 = fmaxf(fabsf(p1.y - pv5) * sc5 - 5.f, 0.f);
    float t7 = fmaxf(fabsf(p1.w - pv7) * sc7 - 5.f, 0.f);
    float t8 = fmaxf(fabsf(p2.x - pv8) * sc8 - 5.f, 0.f);
    float t9 = fmaxf(fabsf(p2.y - pv9) * sc9 - 5.f, 0.f);
    float t11 = fmaxf(fabsf(p2.w - pv11) * sc11 - 5.f, 0.f);
    rest += 0.1f * (t5 * t5 + t7 * t7 + t8 * t8 + t9 * t9 + t11 * t11);
    float acc_rest = sw * rest;

    __syncthreads();   // st reads done; safe to reuse as reduction scratch

    // ---- reductions ----
    const int wave = tid >> 6;
#pragma unroll
    for (int off = 1; off < 64; off <<= 1) {
        acc_mse  += __shfl_xor(acc_mse, off, 64);
        acc_rest += __shfl_xor(acc_rest, off, 64);
    }
#pragma unroll
    for (int off = 4; off < 64; off <<= 1) {
        hn += __shfl_xor(hn, off, 64);
        hd += __shfl_xor(hd, off, 64);
    }

    float* red = reinterpret_cast<float*>(st);   // red[wave*10 + slot]
    if (lane == 0) { red[wave * 10 + 0] = acc_mse; red[wave * 10 + 1] = acc_rest; }
    if (lane < 4)  { red[wave * 10 + 2 + lane] = hn; red[wave * 10 + 6 + lane] = hd; }
    __syncthreads();

    if (tid < 10) {
        float v = 0.f;
#pragma unroll
        for (int w = 0; w < 8; ++w) v += red[w * 10 + tid];
        partials[tid * NBLK + blockIdx.x] = v;
    }
}

__global__ __launch_bounds__(640) void loss_final(
    const float* __restrict__ partials,  // (10, NBLK)
    float* __restrict__ out)
{
    __shared__ float tot[10];
    const int t = threadIdx.x;
    const int c = t >> 6;      // one wave per channel, 10 waves
    const int lane = t & 63;

    const float4* p4 = reinterpret_cast<const float4*>(partials) + (size_t)c * (NBLK / 4);
    float v = 0.f;
#pragma unroll
    for (int i = 0; i < NBLK / 256; ++i) {
        float4 x = p4[i * 64 + lane];
        v += (x.x + x.y) + (x.z + x.w);
    }
#pragma unroll
    for (int off = 32; off; off >>= 1) v += __shfl_down(v, off, 64);
    if (lane == 0) tot[c] = v;
    __syncthreads();

    if (t == 0) {
        const float stepw[4] = {0.48f, 0.24f, 0.16f, 0.12f};
        const float invB = 1.0f / (float)B_TOTAL;
        float mse = tot[0] * invB;
        float phys = tot[1] * invB;
#pragma unroll
        for (int s = 0; s < 4; ++s) {
            float num = tot[2 + s] * invB;
            float den = tot[6 + s] * invB + 1e-6f;
            phys += stepw[s] * (num / den);
        }
        out[0] = mse + 0.1f * phys;
    }
}

extern "C" void kernel_launch(void* const* d_in, const int* in_sizes, int n_in,
                              void* d_out, int out_size, void* d_ws, size_t ws_size,
                              hipStream_t stream) {
    const float* pred   = (const float*)d_in[0];
    const float* target = (const float*)d_in[1];
    const float* inseq  = (const float*)d_in[2];
    const float* scale  = (const float*)d_in[3];
    const float* mean   = (const float*)d_in[4];
    float* out = (float*)d_out;
    float* partials = (float*)d_ws;  // 10 * NBLK floats = 160 KB

    loss_partial<<<NBLK, NTHR, 0, stream>>>(pred, target, inseq, scale, mean, partials);
    loss_final<<<1, 640, 0, stream>>>(partials, out);
}